// Round 1
// baseline (22352.991 us; speedup 1.0000x reference)
//
#include <hip/hip_runtime.h>
#include <hip/hip_bf16.h>
#include <cstddef>

// MatchLSTM (fp32 baseline, round 1)
// Shapes: V=50000, E=300, H=300, C=3, TP=128, TH=64, B=256
// Structure:
//   premise LSTM: 128x k_lstm_gates (fused emb-gather + [x|h] @ [Wih|Whh]^T + gates)
//   ws_hs = h_s @ W_s^T  (one big GEMM, M=32768)
//   hypo loop 64x: k_lstm_gates, k_gemm_tn(q), k_attn (e+softmax+a fused), k_lstm_gates(match)
//   k_fc final
// Workspace use: ~82 MB fp32 (h_s, ws_hs + small state buffers).

#define HDIM 300
#define EDIM 300
#define BATCH 256
#define TPREM 128
#define THYP 64

__device__ __forceinline__ float fast_sigm(float x) {
    return 1.f / (1.f + __expf(-x));
}
__device__ __forceinline__ float fast_tanh(float x) {
    // exact identity tanh(x) = 1 - 2/(e^{2x}+1); no NaN at +/-inf
    float e = __expf(2.f * x);
    return 1.f - 2.f / (e + 1.f);
}

// ---------------------------------------------------------------------------
// Generic gated-LSTM step GEMM.
// A = [A0 | A1] per batch row (A0 optionally an embedding gather via tok/w2v),
// W rows j (j = g*HDIM + hh, gate order i,f,g,o):
//   k <  K0 : W0[j*ld0 + k]
//   k >= K0 : W1[j*ld1 + (k-K0)]
// g = A*W^T + bih + bhh, then c_out = sig(f)*c_in + sig(i)*tanh(g),
// h_out = sig(o)*tanh(c_out).
// Block: 32 b x 16 hh (64 j-cols). 256 threads, thread = 2b x 4gates of 1 hh.
// ---------------------------------------------------------------------------
__global__ void k_lstm_gates(
    const int* __restrict__ tok, const float* __restrict__ w2v,
    const float* __restrict__ A0, int K0,
    const float* __restrict__ A1, int K1,
    const float* __restrict__ W0, int ld0,
    const float* __restrict__ W1, int ld1,
    const float* __restrict__ bih, const float* __restrict__ bhh,
    const float* __restrict__ c_in, float* __restrict__ c_out,
    float* __restrict__ h_out)
{
    constexpr int KT = 32;
    __shared__ __align__(16) float As[KT][34];  // [kk][b_local], pad 2
    __shared__ __align__(16) float Bs[KT][68];  // [kk][hh_l*4+g], pad 4

    const int tid = threadIdx.x;
    const int b0 = blockIdx.x * 32;
    const int hh0 = blockIdx.y * 16;
    const int K = K0 + K1;

    const int pb = tid & 15;   // b-pair index
    const int hl = tid >> 4;   // hh local 0..15

    // fill mappings
    const int fa_b = tid >> 3;            // 0..31
    const int fa_k0 = (tid & 7) * 4;      // 4 consecutive k
    const int fb_c = tid >> 2;            // 0..63 (column = hh_l*4+g)
    const int fb_k0 = (tid & 3) * 8;      // 8 consecutive k
    const int fb_hh = hh0 + (fb_c >> 2);
    const int fb_g = fb_c & 3;
    const int fb_row = fb_g * HDIM + fb_hh;
    const bool fb_valid = fb_hh < HDIM;
    const int ga = b0 + fa_b;
    const int tok_b = tok ? tok[ga] : 0;

    float acc[2][4] = {{0.f,0.f,0.f,0.f},{0.f,0.f,0.f,0.f}};

    for (int k0 = 0; k0 < K; k0 += KT) {
        #pragma unroll
        for (int u = 0; u < 4; ++u) {
            int kk = fa_k0 + u;
            int k = k0 + kk;
            float v = 0.f;
            if (k < K0)      v = tok ? w2v[(size_t)tok_b * K0 + k]
                                     : A0[(size_t)ga * K0 + k];
            else if (k < K)  v = A1[(size_t)ga * K1 + (k - K0)];
            As[kk][fa_b] = v;
        }
        #pragma unroll
        for (int u = 0; u < 8; ++u) {
            int kk = fb_k0 + u;
            int k = k0 + kk;
            float v = 0.f;
            if (fb_valid) {
                if (k < K0)     v = W0[(size_t)fb_row * ld0 + k];
                else if (k < K) v = W1[(size_t)fb_row * ld1 + (k - K0)];
            }
            Bs[kk][fb_c] = v;
        }
        __syncthreads();
        #pragma unroll
        for (int kk = 0; kk < KT; ++kk) {
            float2 av = *(const float2*)&As[kk][pb * 2];
            float4 wv = *(const float4*)&Bs[kk][hl * 4];
            acc[0][0] = fmaf(av.x, wv.x, acc[0][0]);
            acc[0][1] = fmaf(av.x, wv.y, acc[0][1]);
            acc[0][2] = fmaf(av.x, wv.z, acc[0][2]);
            acc[0][3] = fmaf(av.x, wv.w, acc[0][3]);
            acc[1][0] = fmaf(av.y, wv.x, acc[1][0]);
            acc[1][1] = fmaf(av.y, wv.y, acc[1][1]);
            acc[1][2] = fmaf(av.y, wv.z, acc[1][2]);
            acc[1][3] = fmaf(av.y, wv.w, acc[1][3]);
        }
        __syncthreads();
    }

    const int hh = hh0 + hl;
    if (hh < HDIM) {
        float bi = bih[hh] + bhh[hh];
        float bf = bih[HDIM + hh] + bhh[HDIM + hh];
        float bg = bih[2 * HDIM + hh] + bhh[2 * HDIM + hh];
        float bo = bih[3 * HDIM + hh] + bhh[3 * HDIM + hh];
        #pragma unroll
        for (int u = 0; u < 2; ++u) {
            int b = b0 + pb * 2 + u;
            float gi = fast_sigm(acc[u][0] + bi);
            float gf = fast_sigm(acc[u][1] + bf);
            float gg = fast_tanh(acc[u][2] + bg);
            float go = fast_sigm(acc[u][3] + bo);
            float c = gf * c_in[(size_t)b * HDIM + hh] + gi * gg;
            c_out[(size_t)b * HDIM + hh] = c;
            h_out[(size_t)b * HDIM + hh] = go * fast_tanh(c);
        }
    }
}

// ---------------------------------------------------------------------------
// Plain GEMM C[M,N] = A[M,K] * B[N,K]^T with two-part A and two-part B rows.
// ---------------------------------------------------------------------------
template<int BM, int BN, int TM, int TN, int KT>
__global__ void k_gemm_tn(
    const float* __restrict__ A0, int K0,
    const float* __restrict__ A1, int K1,
    const float* __restrict__ B0, int ldb0,
    const float* __restrict__ B1, int ldb1,
    float* __restrict__ C, int M, int N)
{
    __shared__ __align__(16) float As[KT][BM + 4];
    __shared__ __align__(16) float Bs[KT][BN + 4];
    const int tid = threadIdx.x;
    const int m0 = blockIdx.x * BM;
    const int n0 = blockIdx.y * BN;
    const int K = K0 + K1;
    constexpr int TPM = BM / TM;
    const int tm = tid % TPM;
    const int tn = tid / TPM;

    float acc[TM][TN];
    #pragma unroll
    for (int i = 0; i < TM; ++i)
        #pragma unroll
        for (int j = 0; j < TN; ++j) acc[i][j] = 0.f;

    for (int k0 = 0; k0 < K; k0 += KT) {
        for (int i = tid; i < KT * BM; i += 256) {
            int kk = i % KT, ml = i / KT;
            int m = m0 + ml, k = k0 + kk;
            float v = 0.f;
            if (m < M) {
                if (k < K0)     v = A0[(size_t)m * K0 + k];
                else if (k < K) v = A1[(size_t)m * K1 + (k - K0)];
            }
            As[kk][ml] = v;
        }
        for (int i = tid; i < KT * BN; i += 256) {
            int kk = i % KT, nl = i / KT;
            int n = n0 + nl, k = k0 + kk;
            float v = 0.f;
            if (n < N) {
                if (k < K0)     v = B0[(size_t)n * ldb0 + k];
                else if (k < K) v = B1[(size_t)n * ldb1 + (k - K0)];
            }
            Bs[kk][nl] = v;
        }
        __syncthreads();
        #pragma unroll
        for (int kk = 0; kk < KT; ++kk) {
            float a[TM], w[TN];
            #pragma unroll
            for (int i = 0; i < TM; ++i) a[i] = As[kk][tm * TM + i];
            #pragma unroll
            for (int j = 0; j < TN; ++j) w[j] = Bs[kk][tn * TN + j];
            #pragma unroll
            for (int i = 0; i < TM; ++i)
                #pragma unroll
                for (int j = 0; j < TN; ++j)
                    acc[i][j] = fmaf(a[i], w[j], acc[i][j]);
        }
        __syncthreads();
    }
    #pragma unroll
    for (int i = 0; i < TM; ++i) {
        int m = m0 + tm * TM + i;
        if (m >= M) continue;
        #pragma unroll
        for (int j = 0; j < TN; ++j) {
            int n = n0 + tn * TN + j;
            if (n < N) C[(size_t)m * N + n] = acc[i][j];
        }
    }
}

// ---------------------------------------------------------------------------
// Fused attention per hypothesis step. One block per b.
//   e[t] = sum_h w_e[h]*tanh(ws_hs[t,b,h] + q[b,h]);  alpha = softmax_t(e)
//   a[b,h] = sum_t alpha[t]*h_s[t,b,h]
// ---------------------------------------------------------------------------
__global__ void k_attn(const float* __restrict__ ws_hs,
                       const float* __restrict__ h_s,
                       const float* __restrict__ q,
                       const float* __restrict__ w_e,
                       float* __restrict__ a_out)
{
    const int b = blockIdx.x;
    const int tid = threadIdx.x;
    const int lane = tid & 63;
    const int wv = tid >> 6;

    __shared__ float q_s[HDIM];
    __shared__ float we_s[HDIM];
    __shared__ float alpha[TPREM];
    __shared__ float red[4];

    for (int h = tid; h < HDIM; h += 256) {
        q_s[h] = q[(size_t)b * HDIM + h];
        we_s[h] = w_e[h];
    }
    __syncthreads();

    for (int t = wv; t < TPREM; t += 4) {
        const float* row = ws_hs + ((size_t)t * BATCH + b) * HDIM;
        float p = 0.f;
        for (int h = lane; h < HDIM; h += 64)
            p += we_s[h] * fast_tanh(row[h] + q_s[h]);
        #pragma unroll
        for (int off = 32; off; off >>= 1) p += __shfl_xor(p, off, 64);
        if (lane == 0) alpha[t] = p;
    }
    __syncthreads();

    // softmax over the 128 t values (threads 0..127 = waves 0,1)
    if (wv < 2) {
        float ev = alpha[tid];
        float m = ev;
        #pragma unroll
        for (int off = 32; off; off >>= 1) m = fmaxf(m, __shfl_xor(m, off, 64));
        if (lane == 0) red[wv] = m;
        __syncthreads();
        float gm = fmaxf(red[0], red[1]);
        float e = __expf(ev - gm);
        alpha[tid] = e;
        float s = e;
        #pragma unroll
        for (int off = 32; off; off >>= 1) s += __shfl_xor(s, off, 64);
        if (lane == 0) red[2 + wv] = s;
        __syncthreads();
        alpha[tid] *= 1.f / (red[2] + red[3]);
    } else {
        __syncthreads();
        __syncthreads();
    }
    __syncthreads();

    for (int h = tid; h < HDIM; h += 256) {
        const float* hsb = h_s + (size_t)b * HDIM + h;
        float acc = 0.f;
        #pragma unroll 4
        for (int t = 0; t < TPREM; ++t)
            acc = fmaf(alpha[t], hsb[(size_t)t * BATCH * HDIM], acc);
        a_out[(size_t)b * HDIM + h] = acc;
    }
}

// out[b,c] = h_m[b,:] . fc_w[c,:] + fc_b[c]
__global__ void k_fc(const float* __restrict__ h_m,
                     const float* __restrict__ fc_w,
                     const float* __restrict__ fc_b,
                     float* __restrict__ out)
{
    const int b = threadIdx.x;
    float a0 = 0.f, a1 = 0.f, a2 = 0.f;
    for (int h = 0; h < HDIM; ++h) {
        float v = h_m[(size_t)b * HDIM + h];
        a0 = fmaf(v, fc_w[h], a0);
        a1 = fmaf(v, fc_w[HDIM + h], a1);
        a2 = fmaf(v, fc_w[2 * HDIM + h], a2);
    }
    out[b * 3 + 0] = a0 + fc_b[0];
    out[b * 3 + 1] = a1 + fc_b[1];
    out[b * 3 + 2] = a2 + fc_b[2];
}

extern "C" void kernel_launch(void* const* d_in, const int* in_sizes, int n_in,
                              void* d_out, int out_size, void* d_ws, size_t ws_size,
                              hipStream_t stream) {
    (void)in_sizes; (void)n_in; (void)out_size; (void)ws_size;
    const int*   premise    = (const int*)d_in[0];
    const int*   hypothesis = (const int*)d_in[2];
    const float* w2v        = (const float*)d_in[4];
    const float* w_e        = (const float*)d_in[5];
    const float* W_s        = (const float*)d_in[6];
    const float* W_t        = (const float*)d_in[7];
    const float* W_m        = (const float*)d_in[8];
    const float* fc_w       = (const float*)d_in[9];
    const float* fc_b       = (const float*)d_in[10];
    const float* pWih       = (const float*)d_in[11];
    const float* pWhh       = (const float*)d_in[12];
    const float* pbih       = (const float*)d_in[13];
    const float* pbhh       = (const float*)d_in[14];
    const float* hWih       = (const float*)d_in[15];
    const float* hWhh       = (const float*)d_in[16];
    const float* hbih       = (const float*)d_in[17];
    const float* hbhh       = (const float*)d_in[18];
    const float* mWih       = (const float*)d_in[19];
    const float* mbih       = (const float*)d_in[21];
    const float* mbhh       = (const float*)d_in[22];

    const size_t BH = (size_t)BATCH * HDIM;       // 76800
    const size_t SEQ = (size_t)TPREM * BH;        // 9,830,400

    float* ws    = (float*)d_ws;
    float* h_s   = ws;
    float* wshs  = h_s + SEQ;
    float* zeros = wshs + SEQ;
    float* c_p   = zeros + BH;
    float* c_h   = c_p + BH;
    float* c_m   = c_h + BH;
    float* ht0   = c_m + BH;
    float* ht1   = ht0 + BH;
    float* h_m   = ht1 + BH;
    float* qb    = h_m + BH;
    float* ab    = qb + BH;
    // total ~20.35M floats = 81.4 MB

    hipMemsetAsync(zeros, 0, BH * sizeof(float), stream);
    hipMemsetAsync(c_p,   0, BH * sizeof(float), stream);
    hipMemsetAsync(c_h,   0, BH * sizeof(float), stream);
    hipMemsetAsync(h_m,   0, BH * sizeof(float), stream);

    dim3 gGate(BATCH / 32, (HDIM + 15) / 16);   // 8 x 19

    // premise LSTM
    for (int t = 0; t < TPREM; ++t) {
        const float* hp = t ? (h_s + (size_t)(t - 1) * BH) : zeros;
        k_lstm_gates<<<gGate, 256, 0, stream>>>(
            premise + (size_t)t * BATCH, w2v, nullptr, EDIM,
            hp, HDIM, pWih, EDIM, pWhh, HDIM,
            pbih, pbhh, c_p, c_p, h_s + (size_t)t * BH);
    }

    // ws_hs = h_s @ W_s^T   (M = TP*B = 32768, N = K = 300)
    k_gemm_tn<64, 64, 4, 4, 16><<<dim3(TPREM * BATCH / 64, (HDIM + 63) / 64), 256, 0, stream>>>(
        h_s, HDIM, nullptr, 0, W_s, HDIM, nullptr, 0, wshs, TPREM * BATCH, HDIM);

    // hypothesis loop
    for (int k = 0; k < THYP; ++k) {
        const float* hp = k ? ((k & 1) ? ht0 : ht1) : zeros;
        float* hc = (k & 1) ? ht1 : ht0;
        k_lstm_gates<<<gGate, 256, 0, stream>>>(
            hypothesis + (size_t)k * BATCH, w2v, nullptr, EDIM,
            hp, HDIM, hWih, EDIM, hWhh, HDIM,
            hbih, hbhh, c_h, c_h, hc);
        // q = h_t @ W_t^T + h_m @ W_m^T
        k_gemm_tn<16, 64, 1, 4, 16><<<dim3(BATCH / 16, (HDIM + 63) / 64), 256, 0, stream>>>(
            hc, HDIM, h_m, HDIM, W_t, HDIM, W_m, HDIM, qb, BATCH, HDIM);
        k_attn<<<BATCH, 256, 0, stream>>>(wshs, h_s, qb, w_e, ab);
        // match cell: m = [a, h_t], hx = 0
        k_lstm_gates<<<gGate, 256, 0, stream>>>(
            nullptr, nullptr, ab, HDIM,
            hc, HDIM, mWih, 2 * HDIM, mWih + HDIM, 2 * HDIM,
            mbih, mbhh, zeros, c_m, h_m);
    }

    k_fc<<<1, BATCH, 0, stream>>>(h_m, fc_w, fc_b, (float*)d_out);
}